// Round 1
// baseline (47.503 us; speedup 1.0000x reference)
//
#include <hip/hip_runtime.h>
#include <hip/hip_bf16.h>
#include <cmath>

// learnable_computation_tree: out = binary(a3, binary(a1, L0(x), L1(x)), a5*unary(act5, L2(x))+b5)
// where Li(x) = sum_d unary(act_i, x[d]) * W[i][d] + b[i].
// Memory-bound: 256 MB x read + 16 MB out write per call.

__device__ __forceinline__ float dot16_unary(int a, const float xr[16], const float w[16]) {
    float acc = 0.f;
    if (a == 0) {
#pragma unroll
        for (int d = 0; d < 16; ++d) acc = fmaf(xr[d], w[d], acc);
    } else if (a == 1) {
#pragma unroll
        for (int d = 0; d < 16; ++d) acc = fmaf(__sinf(xr[d]), w[d], acc);
    } else if (a == 2) {
#pragma unroll
        for (int d = 0; d < 16; ++d) acc = fmaf(__cosf(xr[d]), w[d], acc);
    } else if (a == 3) {
#pragma unroll
        for (int d = 0; d < 16; ++d) acc = fmaf(xr[d] * xr[d], w[d], acc);
    } else {
#pragma unroll
        for (int d = 0; d < 16; ++d) acc = fmaf(tanhf(xr[d]), w[d], acc);
    }
    return acc;
}

__device__ __forceinline__ float unary1(int a, float z) {
    switch (a) {
        case 1: return __sinf(z);
        case 2: return __cosf(z);
        case 3: return z * z;
        case 4: return tanhf(z);
        default: return z;
    }
}

__global__ void __launch_bounds__(256) tree_kernel(
    const float4* __restrict__ x4, const int* __restrict__ act,
    const float* __restrict__ W, const float* __restrict__ b,
    const float* __restrict__ a5p, const float* __restrict__ b5p,
    float* __restrict__ out, int n) {
    // Wave-uniform node actions (6 ints, L2-resident after first wave).
    const int a0 = act[0], a1 = act[1], a2 = act[2];
    const int a3 = act[3], a4 = act[4], a5 = act[5];

    // Preload W [3][16] into registers; all indices compile-time constant.
    float Wr[48];
    const float4* W4 = reinterpret_cast<const float4*>(W);
#pragma unroll
    for (int i = 0; i < 12; ++i) {
        float4 t = W4[i];
        Wr[4 * i + 0] = t.x; Wr[4 * i + 1] = t.y;
        Wr[4 * i + 2] = t.z; Wr[4 * i + 3] = t.w;
    }
    const float b0 = b[0], b1 = b[1], b2 = b[2];
    const float a5v = a5p[0], b5v = b5p[0];

    const int tid = blockIdx.x * blockDim.x + threadIdx.x;
    const int stride = gridDim.x * blockDim.x;
    for (int r = tid; r < n; r += stride) {
        // Load one row: 4x float4 = 64 B contiguous per lane.
        float xr[16];
        const float4* p = x4 + (size_t)r * 4;
#pragma unroll
        for (int j = 0; j < 4; ++j) {
            float4 t = p[j];
            xr[4 * j + 0] = t.x; xr[4 * j + 1] = t.y;
            xr[4 * j + 2] = t.z; xr[4 * j + 3] = t.w;
        }
        const float v0 = dot16_unary(a0, xr, &Wr[0])  + b0;
        const float v2 = dot16_unary(a2, xr, &Wr[16]) + b1;
        const float v4 = dot16_unary(a4, xr, &Wr[32]) + b2;
        const float left  = (a1 == 1) ? (v0 * v2) : (v0 + v2);
        const float right = fmaf(a5v, unary1(a5, v4), b5v);
        out[r] = (a3 == 1) ? (left * right) : (left + right);
    }
}

extern "C" void kernel_launch(void* const* d_in, const int* in_sizes, int n_in,
                              void* d_out, int out_size, void* d_ws, size_t ws_size,
                              hipStream_t stream) {
    const float* x   = (const float*)d_in[0];   // [N,16] fp32
    const int*   act = (const int*)d_in[1];     // [6] int32
    const float* W   = (const float*)d_in[2];   // [3,16] fp32
    const float* b   = (const float*)d_in[3];   // [3] fp32
    const float* a5  = (const float*)d_in[4];   // [1] fp32
    const float* b5  = (const float*)d_in[5];   // [1] fp32
    float* out = (float*)d_out;                 // [N] fp32 (shape [N,1])
    const int n = out_size;

    const int block = 256;
    const int grid = 2048;  // grid-stride: ~7.6 rows/thread at N=4M
    hipLaunchKernelGGL(tree_kernel, dim3(grid), dim3(block), 0, stream,
                       (const float4*)x, act, W, b, a5, b5, out, n);
}